// Round 2
// baseline (1380.370 us; speedup 1.0000x reference)
//
#include <hip/hip_runtime.h>
#include <hip/hip_bf16.h>

#define Bq 16
#define Tq 256
#define Vq 18000
#define NSq 30
#define Lq 10
#define Gq 3
#define Hq 400
#define Nq (NSq * Bq)      // 480
#define H3q (3 * Hq)       // 1200
#define CHq 9000           // softmax LDS chunk (2 chunks cover V)

typedef __bf16 bf16;
typedef __bf16 bf16x4 __attribute__((ext_vector_type(4)));
typedef __bf16 bf16x8 __attribute__((ext_vector_type(8)));
typedef float floatx16 __attribute__((ext_vector_type(16)));

// ---------------------------------------------------------------------------
// K-1: f32 -> bf16 conversion (vectorized by 4), run once per launch.
// ---------------------------------------------------------------------------
__global__ __launch_bounds__(256) void k_f2b4(
    const float* __restrict__ src, bf16* __restrict__ dst, const int n4)
{
    int i = blockIdx.x * 256 + threadIdx.x;
    if (i >= n4) return;
    const float4 v = ((const float4*)src)[i];
    bf16x4 o;
    o[0] = (bf16)v.x; o[1] = (bf16)v.y; o[2] = (bf16)v.z; o[3] = (bf16)v.w;
    ((bf16x4*)dst)[i] = o;
}

// ---------------------------------------------------------------------------
// K0: build decoder input xb (bf16) + x (f32); step 0 also inits h + hb.
// ---------------------------------------------------------------------------
__global__ __launch_bounds__(256) void k_prep(
    const float* __restrict__ slot_emb, const int* __restrict__ dom,
    const int* __restrict__ slo, const bf16* __restrict__ embb,
    const int* __restrict__ tgt, const float* __restrict__ ehid,
    float* __restrict__ h, bf16* __restrict__ hb, bf16* __restrict__ xb,
    const int step)
{
    int i = blockIdx.x * 256 + threadIdx.x;
    if (i >= Nq * Hq) return;
    int n = i / Hq, k = i - n * Hq;
    int s = n / Bq, b = n & (Bq - 1);
    if (step == 0) {
        float v = slot_emb[dom[s] * Hq + k] + slot_emb[slo[s] * Hq + k];
        xb[i] = (bf16)v;
        float hv = ehid[b * Hq + k];
        h[i] = hv;
        hb[i] = (bf16)hv;
    } else {
        int tv = tgt[(b * NSq + s) * Lq + (step - 1)];
        xb[i] = embb[(size_t)tv * Hq + k];
    }
}

// ---------------------------------------------------------------------------
// K1: GRU pre-activations via MFMA.  gi = xb @ W_ih^T, gh = hb @ W_hh^T.
// 32x32x16 bf16 MFMA, K=400 = 25*16.  A-frag: m=lane&31, k=(lane>>5)*8+j.
// C/D: col=lane&31, row=(reg&3)+8*(reg>>2)+4*(lane>>5).
// grid = (38 col tiles, 4 row-group sets, 2 [ih|hh]), block = 256 (4 waves).
// ---------------------------------------------------------------------------
__global__ __launch_bounds__(256) void k_gru_gemm(
    const bf16* __restrict__ xb, const bf16* __restrict__ hb,
    const bf16* __restrict__ w_ih, const bf16* __restrict__ w_hh,
    float* __restrict__ gi, float* __restrict__ gh)
{
    const int ct = blockIdx.x;
    const int which = blockIdx.z;
    const int wave = threadIdx.x >> 6;
    const int lane = threadIdx.x & 63;
    const int g = blockIdx.y * 4 + wave;   // row group (32 rows each), 15 total
    if (g >= 15) return;
    const bf16* A = which ? hb : xb;
    const bf16* W = which ? w_hh : w_ih;
    float* O = which ? gh : gi;
    const int m = lane & 31;
    const int kh = (lane >> 5) * 8;
    const int row = g * 32 + m;            // < 480 always
    int col = ct * 32 + m;
    if (col >= H3q) col = H3q - 1;         // clamp load, store guarded
    const bf16* Ap = A + row * Hq + kh;
    const bf16* Wp = W + col * Hq + kh;
    floatx16 acc;
    #pragma unroll
    for (int r = 0; r < 16; ++r) acc[r] = 0.f;
    for (int kt = 0; kt < 25; ++kt) {
        bf16x8 a = *(const bf16x8*)(Ap + kt * 16);
        bf16x8 w = *(const bf16x8*)(Wp + kt * 16);
        acc = __builtin_amdgcn_mfma_f32_32x32x16_bf16(a, w, acc, 0, 0, 0);
    }
    const int j = ct * 32 + (lane & 31);
    if (j < H3q) {
        const int rbase = g * 32 + 4 * (lane >> 5);
        #pragma unroll
        for (int r = 0; r < 16; ++r) {
            int rr = rbase + (r & 3) + 8 * (r >> 2);
            O[rr * H3q + j] = acc[r];
        }
    }
}

// ---------------------------------------------------------------------------
// K2: GRU nonlinearity + attention softmax + context + switch (+gates @ step0)
// one block per row n (480 blocks, 256 threads).
// ---------------------------------------------------------------------------
__global__ __launch_bounds__(256) void k_gru_attn(
    const float* __restrict__ gi, const float* __restrict__ gh,
    const float* __restrict__ b_ih, const float* __restrict__ b_hh,
    float* __restrict__ h, bf16* __restrict__ hb,
    const bf16* __restrict__ xb, const bf16* __restrict__ encb,
    const int* __restrict__ lens, const float* __restrict__ w_ratio,
    const float* __restrict__ b_ratio, const float* __restrict__ w_gate,
    const float* __restrict__ b_gate, float* __restrict__ prob,
    float* __restrict__ swp, float* __restrict__ out_gates, const int step)
{
    const int n = blockIdx.x;
    const int b = n & (Bq - 1);
    const int tid = threadIdx.x;
    __shared__ float s_h[Hq];
    __shared__ float s_c[Hq];
    __shared__ float s_p[Tq];
    __shared__ float s_red[4];

    const float* gin = gi + n * H3q;
    const float* ghn = gh + n * H3q;
    for (int k = tid; k < Hq; k += 256) {
        float ir = gin[k]          + b_ih[k];
        float hr = ghn[k]          + b_hh[k];
        float iz = gin[Hq + k]     + b_ih[Hq + k];
        float hz = ghn[Hq + k]     + b_hh[Hq + k];
        float in_ = gin[2*Hq + k]  + b_ih[2*Hq + k];
        float hn_ = ghn[2*Hq + k]  + b_hh[2*Hq + k];
        float r = 1.f / (1.f + __expf(-(ir + hr)));
        float z = 1.f / (1.f + __expf(-(iz + hz)));
        float nn = tanhf(in_ + r * hn_);
        float hp = h[n * Hq + k];
        float hv = (1.f - z) * nn + z * hp;
        s_h[k] = hv;
        h[n * Hq + k] = hv;
        hb[n * Hq + k] = (bf16)hv;
    }
    __syncthreads();

    // scores: thread t over T=256
    const int t = tid;
    const bf16* erow = encb + (size_t)(b * Tq + t) * Hq;
    float sc = 0.f;
    #pragma unroll 5
    for (int kc = 0; kc < Hq / 8; ++kc) {
        bf16x8 e = *(const bf16x8*)(erow + kc * 8);
        #pragma unroll
        for (int j = 0; j < 8; ++j) sc += s_h[kc * 8 + j] * (float)e[j];
    }
    const int len = lens[b];
    float score = (t < len) ? sc : -1e9f;

    float mx = score;
    for (int off = 32; off > 0; off >>= 1) mx = fmaxf(mx, __shfl_xor(mx, off, 64));
    if ((tid & 63) == 0) s_red[tid >> 6] = mx;
    __syncthreads();
    mx = fmaxf(fmaxf(s_red[0], s_red[1]), fmaxf(s_red[2], s_red[3]));
    float ev = __expf(score - mx);
    float sm = ev;
    for (int off = 32; off > 0; off >>= 1) sm += __shfl_xor(sm, off, 64);
    __syncthreads();
    if ((tid & 63) == 0) s_red[tid >> 6] = sm;
    __syncthreads();
    sm = s_red[0] + s_red[1] + s_red[2] + s_red[3];
    float p = ev / sm;
    s_p[t] = p;
    prob[n * Tq + t] = p;
    __syncthreads();

    // context[k] = sum_t p[t] * enc[b][t][k]
    for (int k = tid; k < Hq; k += 256) {
        float c = 0.f;
        const bf16* ecol = encb + (size_t)b * Tq * Hq + k;
        for (int tt = 0; tt < Tq; ++tt) c += s_p[tt] * (float)ecol[tt * Hq];
        s_c[k] = c;
    }
    __syncthreads();

    // switch = sigmoid([h_new, ctx, x] . w_ratio + b_ratio)
    float part = 0.f;
    for (int k = tid; k < Hq; k += 256) {
        part += w_ratio[k]        * s_h[k]
              + w_ratio[Hq + k]   * s_c[k]
              + w_ratio[2*Hq + k] * (float)xb[n * Hq + k];
    }
    for (int off = 32; off > 0; off >>= 1) part += __shfl_xor(part, off, 64);
    __syncthreads();
    if ((tid & 63) == 0) s_red[tid >> 6] = part;
    __syncthreads();
    if (tid == 0) {
        float tot = s_red[0] + s_red[1] + s_red[2] + s_red[3] + b_ratio[0];
        swp[n] = 1.f / (1.f + __expf(-tot));
    }

    if (step == 0) {  // gates from context of step 0
        for (int gg = 0; gg < Gq; ++gg) {
            float pg = 0.f;
            for (int k = tid; k < Hq; k += 256)
                pg += w_gate[gg * Hq + k] * s_c[k];
            for (int off = 32; off > 0; off >>= 1) pg += __shfl_xor(pg, off, 64);
            __syncthreads();
            if ((tid & 63) == 0) s_red[tid >> 6] = pg;
            __syncthreads();
            if (tid == 0)
                out_gates[n * Gq + gg] =
                    s_red[0] + s_red[1] + s_red[2] + s_red[3] + b_gate[gg];
        }
    }
}

// ---------------------------------------------------------------------------
// K3: vocab logits GEMM: logits[n][v] = hb[n] . embb[v].  563 col-tile blocks,
// 4 waves each; wave handles row groups {w, w+4, w+8, w+12} (skip >=15).
// ---------------------------------------------------------------------------
__global__ __launch_bounds__(256) void k_vocab_gemm(
    const bf16* __restrict__ hb, const bf16* __restrict__ embb,
    float* __restrict__ logits)
{
    const int ct = blockIdx.x;       // 0..562
    const int wave = threadIdx.x >> 6;
    const int lane = threadIdx.x & 63;
    const int m = lane & 31;
    const int kh = (lane >> 5) * 8;
    int col = ct * 32 + m;
    if (col >= Vq) col = Vq - 1;
    const bf16* Ep = embb + (size_t)col * Hq + kh;
    floatx16 acc[4];
    #pragma unroll
    for (int i = 0; i < 4; ++i)
        #pragma unroll
        for (int r = 0; r < 16; ++r) acc[i][r] = 0.f;

    for (int kt = 0; kt < 25; ++kt) {
        bf16x8 e = *(const bf16x8*)(Ep + kt * 16);
        #pragma unroll
        for (int i = 0; i < 4; ++i) {
            int g = wave + 4 * i;
            if (g < 15) {
                bf16x8 a = *(const bf16x8*)(hb + (g * 32 + m) * Hq + kh + kt * 16);
                acc[i] = __builtin_amdgcn_mfma_f32_32x32x16_bf16(a, e, acc[i], 0, 0, 0);
            }
        }
    }
    const int j = ct * 32 + (lane & 31);
    if (j < Vq) {
        #pragma unroll
        for (int i = 0; i < 4; ++i) {
            int g = wave + 4 * i;
            if (g < 15) {
                const int rbase = g * 32 + 4 * (lane >> 5);
                #pragma unroll
                for (int r = 0; r < 16; ++r) {
                    int rr = rbase + (r & 3) + 8 * (r >> 2);
                    logits[(size_t)rr * Vq + j] = acc[i][r];
                }
            }
        }
    }
}

// ---------------------------------------------------------------------------
// K4: online softmax over V, pointer-generator mix + scatter, f32 store.
// one block per row (480 blocks, 512 threads), 36 KB LDS chunking.
// ---------------------------------------------------------------------------
__global__ __launch_bounds__(512) void k_softmax_final(
    const float* __restrict__ logits, const float* __restrict__ prob,
    const float* __restrict__ swp, const int* __restrict__ story,
    float* __restrict__ out, const int step)
{
    __shared__ float s_chunk[CHq];
    __shared__ float s_red[8];
    __shared__ float s_red2[8];
    __shared__ float s_MS[2];
    const int n = blockIdx.x;
    const int b = n & (Bq - 1);
    const int tid = threadIdx.x;
    const float* lr = logits + (size_t)n * Vq;

    // online (max, sum) over the row
    float m = -1e30f, s = 0.f;
    for (int v = tid; v < Vq; v += 512) {
        float x = lr[v];
        float nm = fmaxf(m, x);
        s = s * __expf(m - nm) + __expf(x - nm);
        m = nm;
    }
    for (int off = 32; off > 0; off >>= 1) {
        float om = __shfl_xor(m, off, 64);
        float os = __shfl_xor(s, off, 64);
        float nm = fmaxf(m, om);
        s = s * __expf(m - nm) + os * __expf(om - nm);
        m = nm;
    }
    if ((tid & 63) == 0) { s_red[tid >> 6] = m; s_red2[tid >> 6] = s; }
    __syncthreads();
    if (tid == 0) {
        float M = -1e30f;
        for (int i = 0; i < 8; ++i) M = fmaxf(M, s_red[i]);
        float S = 0.f;
        for (int i = 0; i < 8; ++i) S += s_red2[i] * __expf(s_red[i] - M);
        s_MS[0] = M; s_MS[1] = S;
    }
    __syncthreads();
    const float M = s_MS[0];
    const float swv = swp[n];
    const float scale = swv / s_MS[1];
    float* orow = out + ((size_t)n * Lq + step) * Vq;

    #pragma unroll
    for (int c = 0; c < 2; ++c) {
        const int c0 = c * CHq;
        for (int v = tid; v < CHq; v += 512)
            s_chunk[v] = __expf(lr[c0 + v] - M) * scale;
        __syncthreads();
        if (tid < Tq) {
            int idx = story[b * Tq + tid];
            if (idx >= c0 && idx < c0 + CHq) {
                float add = (1.f - swv) * prob[n * Tq + tid];
                atomicAdd(&s_chunk[idx - c0], add);
            }
        }
        __syncthreads();
        for (int v = tid; v < CHq; v += 512)
            orow[c0 + v] = s_chunk[v];
        __syncthreads();
    }
}

// ---------------------------------------------------------------------------
extern "C" void kernel_launch(void* const* d_in, const int* in_sizes, int n_in,
                              void* d_out, int out_size, void* d_ws, size_t ws_size,
                              hipStream_t stream)
{
    const float* ehid    = (const float*)d_in[0];
    const float* enc     = (const float*)d_in[1];
    const float* emb     = (const float*)d_in[2];
    const float* w_ih    = (const float*)d_in[3];
    const float* w_hh    = (const float*)d_in[4];
    const float* b_ih    = (const float*)d_in[5];
    const float* b_hh    = (const float*)d_in[6];
    const float* w_ratio = (const float*)d_in[7];
    const float* b_ratio = (const float*)d_in[8];
    const float* w_gate  = (const float*)d_in[9];
    const float* b_gate  = (const float*)d_in[10];
    const float* slot_emb= (const float*)d_in[11];
    const int*  lens     = (const int*)d_in[12];
    const int*  story    = (const int*)d_in[13];
    const int*  tgt      = (const int*)d_in[14];
    const int*  dom      = (const int*)d_in[15];
    const int*  slo      = (const int*)d_in[16];

    float* out = (float*)d_out;
    float* out_gates = out + (size_t)NSq * Bq * Lq * Vq;

    char* w = (char*)d_ws;
    size_t off = 0;
    auto alloc = [&](size_t bytes) -> void* {
        void* p = (void*)(w + off);
        off += (bytes + 255) & ~(size_t)255;
        return p;
    };
    bf16*  xb     = (bf16*)alloc((size_t)Nq * Hq * 2);
    bf16*  hb     = (bf16*)alloc((size_t)Nq * Hq * 2);
    float* h      = (float*)alloc((size_t)Nq * Hq * 4);
    float* gi     = (float*)alloc((size_t)Nq * H3q * 4);
    float* gh     = (float*)alloc((size_t)Nq * H3q * 4);
    float* prob   = (float*)alloc((size_t)Nq * Tq * 4);
    float* swp    = (float*)alloc((size_t)Nq * 4);
    float* logits = (float*)alloc((size_t)Nq * Vq * 4);
    bf16*  embb   = (bf16*)alloc((size_t)Vq * Hq * 2);
    bf16*  wbih   = (bf16*)alloc((size_t)H3q * Hq * 2);
    bf16*  wbhh   = (bf16*)alloc((size_t)H3q * Hq * 2);
    bf16*  encb   = (bf16*)alloc((size_t)Bq * Tq * Hq * 2);

    // one-time f32 -> bf16 conversions
    {
        int n4;
        n4 = (Vq * Hq) / 4;
        k_f2b4<<<dim3((n4 + 255) / 256), dim3(256), 0, stream>>>(emb, embb, n4);
        n4 = (H3q * Hq) / 4;
        k_f2b4<<<dim3((n4 + 255) / 256), dim3(256), 0, stream>>>(w_ih, wbih, n4);
        k_f2b4<<<dim3((n4 + 255) / 256), dim3(256), 0, stream>>>(w_hh, wbhh, n4);
        n4 = (Bq * Tq * Hq) / 4;
        k_f2b4<<<dim3((n4 + 255) / 256), dim3(256), 0, stream>>>(enc, encb, n4);
    }

    for (int step = 0; step < Lq; ++step) {
        k_prep<<<dim3((Nq * Hq + 255) / 256), dim3(256), 0, stream>>>(
            slot_emb, dom, slo, embb, tgt, ehid, h, hb, xb, step);
        k_gru_gemm<<<dim3(38, 4, 2), dim3(256), 0, stream>>>(
            xb, hb, wbih, wbhh, gi, gh);
        k_gru_attn<<<dim3(Nq), dim3(256), 0, stream>>>(
            gi, gh, b_ih, b_hh, h, hb, xb, encb, lens, w_ratio, b_ratio,
            w_gate, b_gate, prob, swp, out_gates, step);
        k_vocab_gemm<<<dim3(563), dim3(256), 0, stream>>>(hb, embb, logits);
        k_softmax_final<<<dim3(Nq), dim3(512), 0, stream>>>(
            logits, prob, swp, story, out, step);
    }
}